// Round 2
// baseline (1947.458 us; speedup 1.0000x reference)
//
#include <hip/hip_runtime.h>
#include <hip/hip_fp16.h>
#include <stdint.h>
#include <stddef.h>

// LSTM B=512,T=128,D=256,H=256,C=128, gates (i,j,f,o), FORGET_BIAS=1.
// R11 = R10 with the recurrent loop row-split 4->1 (512 blocks x 1 row):
//   Per-block MFMA work is row-invariant (each block needs its full h for
//   K=256 next step), so 1-row blocks cost the same per block but give TWO
//   independent blocks per CU (4 waves/SIMD). Counters showed MFMA (23%) and
//   VALU (26%) phases serialize inside one lockstep block; co-resident
//   independent blocks overlap them. h is self-replicated into M-rows
//   0/4/8/12 (all quads publish identical h via the existing 4*quad write),
//   z-extract select becomes block-uniform (sel=R&3), z folds into the acc
//   initializer (kills 32 zero-movs + 8 adds on the post-MFMA tail), and
//   sibling blocks sharing z-uint2s are XCD-colocated by a bijective swizzle.

typedef __attribute__((ext_vector_type(8))) __bf16 bf16x8;
typedef __attribute__((ext_vector_type(4))) __bf16 bf16x4;
typedef __attribute__((ext_vector_type(4))) float  f32x4;
typedef __attribute__((ext_vector_type(8))) int    i32x8;

#define LDH   264          // bf16 row stride (xproj A-tile, out staging)
#define LDF   272          // fp8 Ht row stride in bytes (256 + 16)
#define ZPS   2097152ull   // Zx plane stride in uint2 (32*128*8*64)
#define SONE  0x7F7F7F7F   // E8M0 unit scales (all blocks = 2^0)

__device__ __forceinline__ f32x4 mfma_bf16(bf16x8 a, bf16x8 b, f32x4 c) {
    return __builtin_amdgcn_mfma_f32_16x16x32_bf16(a, b, c, 0, 0, 0);
}
#define EXP2(x) __builtin_amdgcn_exp2f(x)
#define RCP(x)  __builtin_amdgcn_rcpf(x)
#define L2E  1.442695040f
#define L2E2 2.885390082f

// ---------------- 1) weight shuffle ----------------
// Wx -> bf16 16x16x32 B-frags (for xproj). Wh -> fp8 K=128 B-frags:
// frag (ng, kt128): lane holds B[k=kt128*128+quad*32+j][n=ng*16+l16], j=0..31.
__global__ __launch_bounds__(256) void shuffle_w(const float* __restrict__ Wk,
                                                 __bf16* __restrict__ WxF,
                                                 unsigned char* __restrict__ WhF) {
    int id = blockIdx.x * 256 + threadIdx.x;
    if (id < 32768) {                                  // Wx part (rows 0..255)
        int lane = id & 63, kt = (id >> 6) & 7, nt = id >> 9;
        int quad = lane >> 4, l16 = lane & 15;
        const float* src = Wk + (size_t)(kt * 32 + quad * 8) * 1024 + nt * 16 + l16;
        __bf16* dst = WxF + ((size_t)(nt * 8 + kt) * 64 + lane) * 8;
#pragma unroll
        for (int j = 0; j < 8; ++j) dst[j] = (__bf16)src[(size_t)j * 1024];
    } else if (id < 40960) {                           // Wh part (rows 256..511)
        int i = id - 32768;
        int lane = i & 63, kt = (i >> 6) & 1, ng = i >> 7;
        int n = ng * 16 + (lane & 15);
        int kb = 256 + kt * 128 + (lane >> 4) * 32;
        int* dst = (int*)(WhF + (((size_t)ng * 2 + kt) * 64 + lane) * 32);
#pragma unroll
        for (int d = 0; d < 8; ++d) {
            float w0 = Wk[(size_t)(kb + 4 * d + 0) * 1024 + n];
            float w1 = Wk[(size_t)(kb + 4 * d + 1) * 1024 + n];
            float w2 = Wk[(size_t)(kb + 4 * d + 2) * 1024 + n];
            float w3 = Wk[(size_t)(kb + 4 * d + 3) * 1024 + n];
            int lo = __builtin_amdgcn_cvt_pk_fp8_f32(w0, w1, 0, false);
            dst[d]  = __builtin_amdgcn_cvt_pk_fp8_f32(w2, w3, lo, true);
        }
    }
}

// ---------------- 2) x-projection (plane-separated Zx) — as R5/R8 ----------------
__global__ __launch_bounds__(512, 2) void xproj(const float* __restrict__ x,
        const __bf16* __restrict__ WxF, const float* __restrict__ bias,
        uint2* __restrict__ Zx) {
    __shared__ __attribute__((aligned(16))) __bf16 At[64 * LDH];
    const int tid = threadIdx.x, wv = tid >> 6, lane = tid & 63;
    const int l16 = lane & 15, quad = lane >> 4;
    const int rb = blockIdx.x & 31, tg = blockIdx.x >> 5;

#pragma unroll
    for (int rr = 0; rr < 8; ++rr) {
        int Arow = wv * 8 + rr;
        int tt = Arow >> 4, r = Arow & 15;
        const float4 xv = *((const float4*)(x + ((size_t)(rb * 16 + r) * 128 + tg * 4 + tt) * 256) + lane);
        bf16x4 xb = { (__bf16)xv.x, (__bf16)xv.y, (__bf16)xv.z, (__bf16)xv.w };
        *(bf16x4*)&At[Arow * LDH + lane * 4] = xb;
    }
    __syncthreads();

    f32x4 acc[4][8];
#pragma unroll
    for (int tt = 0; tt < 4; ++tt)
#pragma unroll
        for (int nt = 0; nt < 8; ++nt) acc[tt][nt] = (f32x4){0.f, 0.f, 0.f, 0.f};

#pragma unroll
    for (int kt = 0; kt < 8; ++kt) {
        bf16x8 af[4];
#pragma unroll
        for (int tt = 0; tt < 4; ++tt)
            af[tt] = *(const bf16x8*)&At[(tt * 16 + l16) * LDH + kt * 32 + quad * 8];
#pragma unroll
        for (int nt = 0; nt < 8; ++nt) {
            bf16x8 wf = *(const bf16x8*)&WxF[(((size_t)(wv * 8 + nt) * 8 + kt) * 64 + lane) * 8];
#pragma unroll
            for (int tt = 0; tt < 4; ++tt) acc[tt][nt] = mfma_bf16(af[tt], wf, acc[tt][nt]);
        }
    }

#pragma unroll
    for (int nt = 0; nt < 8; ++nt) {
        int col = wv * 128 + nt * 16 + l16;
        float bb = bias[col] + ((col >= 512 && col < 768) ? 1.0f : 0.0f);
#pragma unroll
        for (int tt = 0; tt < 4; ++tt) {
            int t = tg * 4 + tt;
            union { __half h[4]; uint2 u; } pk;
#pragma unroll
            for (int r = 0; r < 4; ++r) pk.h[r] = __float2half(acc[tt][nt][r] + bb);
            Zx[(size_t)wv * ZPS + ((size_t)(rb * 128 + t) * 8 + nt) * 64 + lane] = pk.u;
        }
    }
}

// ---------------- 3) recurrent loop: 512 blocks x 1 batch row ----------------
// One timestep. Reads h(t) from HtF[RBUF], writes h(t+1) to HtF[WBUF].
// ZB holds z(t) (issued >= 2 steps ago); z is extracted (block-uniform sel)
// straight into the MFMA accumulator initializer, then the SAME registers
// are reloaded with z(t+2). End barrier orders ONLY lgkm (LDS publish);
// global loads stay in flight across it (counted vmcnt at next-but-one use).
#define LSTM_STEP(TT, ZB, RBUF, WBUF)                                          \
    {                                                                          \
        i32x8 afr[2];                                                          \
        _Pragma("unroll")                                                      \
        for (int kt = 0; kt < 2; ++kt) {                                       \
            const uint4* ap = (const uint4*)&HtF[RBUF][l16 * LDF + kt * 128 + quad * 32]; \
            uint4 lo = ap[0], hi = ap[1];                                      \
            afr[kt] = (i32x8){(int)lo.x, (int)lo.y, (int)lo.z, (int)lo.w,      \
                              (int)hi.x, (int)hi.y, (int)hi.z, (int)hi.w};     \
        }                                                                      \
        f32x4 acc[8];                                                          \
        _Pragma("unroll")                                                      \
        for (int p = 0; p < 8; ++p) {                                          \
            unsigned w = (sel & 2) ? ZB[p].y : ZB[p].x;                        \
            w = (sel & 1) ? (w >> 16) : (w & 0xffff);                          \
            union { unsigned short u; __half h; } cv; cv.u = (unsigned short)w;\
            acc[p] = (f32x4){__half2float(cv.h), 0.f, 0.f, 0.f};               \
        }                                                                      \
        {                                                                      \
            int tl = ((TT) + 2 > 127) ? 127 : ((TT) + 2);                      \
            size_t zi = zi0 + (size_t)tl * 512;                                \
            _Pragma("unroll")                                                  \
            for (int p = 0; p < 8; ++p) ZB[p] = Zx[p * ZPS + zi];              \
        }                                                                      \
        _Pragma("unroll")                                                      \
        for (int kt = 0; kt < 2; ++kt)                                         \
            _Pragma("unroll")                                                  \
            for (int p = 0; p < 8; ++p)                                        \
                acc[p] = __builtin_amdgcn_mfma_scale_f32_16x16x128_f8f6f4(     \
                    afr[kt], wreg[p * 2 + kt], acc[p], 0, 0, 0, SONE, 0, SONE);\
        unsigned char* ldsw = &HtF[WBUF][0];                                   \
        _Pragma("unroll")                                                      \
        for (int hf = 0; hf < 2; ++hf) {                                       \
            float iv = acc[0 + hf][0];                                         \
            float jv = acc[2 + hf][0];                                         \
            float fv = acc[4 + hf][0];                                         \
            float ov = acc[6 + hf][0];                                         \
            float si = RCP(1.f + EXP2(-L2E * iv));                             \
            float sf = RCP(1.f + EXP2(-L2E * fv));                             \
            float so = RCP(1.f + EXP2(-L2E * ov));                             \
            float tj = 2.f * RCP(1.f + EXP2(-L2E2 * jv)) - 1.f;                \
            float c = c_[hf] * sf + si * tj;                                   \
            c_[hf] = c;                                                        \
            float tc = 2.f * RCP(1.f + EXP2(-L2E2 * c)) - 1.f;                 \
            float h = tc * so;                                                 \
            hr[hf] = h;                                                        \
            unsigned pb = (unsigned)__builtin_amdgcn_cvt_pk_fp8_f32(h, h, 0, false); \
            ldsw[(4 * quad) * LDF + hf * 128 + col0] = (unsigned char)pb;      \
        }                                                                      \
        /* publish h(t+1): order LDS only; leave global loads in flight */     \
        asm volatile("s_waitcnt lgkmcnt(0)\n\ts_barrier" ::: "memory");        \
    }

__global__ __launch_bounds__(512, 4) void lstm_rec(const unsigned char* __restrict__ WhF,
        const uint2* __restrict__ Zx, const float* __restrict__ wout,
        const float* __restrict__ bout, float* __restrict__ out) {
    // Ht: plain fp8 matrix [16 rows][272 B], double-buffered. The single
    // batch row is REPLICATED into rows 0,4,8,12 (each quad publishes its
    // copy); other rows stay zero (m-padding).
    __shared__ __attribute__((aligned(16))) unsigned char HtF[2][16 * LDF];
    __shared__ __attribute__((aligned(16))) __bf16 HtB[16 * LDH];   // out staging
    const int tid = threadIdx.x, wv = tid >> 6, lane = tid & 63;
    const int l16 = lane & 15, quad = lane >> 4;
    // XCD-colocating bijective swizzle (512 = 8 XCDs x 64): the 4 sibling
    // blocks sharing each packed z-uint2 (same R>>2) land on one XCD's L2.
    const int R = ((blockIdx.x & 7) << 6) | (blockIdx.x >> 3);  // batch row
    const int sel = R & 3;                   // half-select inside z uint2 (uniform)

    // Wh MX B-frags: 16 x v8i32 = 128 regs (p = g*2+hf, kt128 = 0,1)
    i32x8 wreg[16];
#pragma unroll
    for (int p = 0; p < 8; ++p) {
        int ng = (p >> 1) * 16 + (p & 1) * 8 + wv;   // cols g*256+hf*128+wv*16+l16
#pragma unroll
        for (int kt = 0; kt < 2; ++kt) {
            const uint4* wp = (const uint4*)(WhF + (((size_t)ng * 2 + kt) * 64 + lane) * 32);
            uint4 lo = wp[0], hi = wp[1];
            wreg[p * 2 + kt] = (i32x8){(int)lo.x, (int)lo.y, (int)lo.z, (int)lo.w,
                                       (int)hi.x, (int)hi.y, (int)hi.z, (int)hi.w};
        }
    }
    for (int i = tid; i < (16 * LDF * 2) / 4; i += 512) ((uint*)HtF[0])[i] = 0u;

    const int col0 = wv * 16 + l16;
    float c_[2] = {0.f, 0.f};
    float hr[2] = {0.f, 0.f};
    // z uint2 for row R lives at lane' = ((R>>2)&3)*16 + l16 of group R>>4,
    // plane p, half #sel. Address is quad-independent (dup loads coalesce).
    const size_t zi0 = ((size_t)(R >> 4) * 1024 + wv) * 64
                     + (size_t)((R >> 2) & 3) * 16 + l16;

    // depth-2 prefetch: zA = z(0), zB = z(1)
    uint2 zA[8], zB[8];
#pragma unroll
    for (int p = 0; p < 8; ++p) zA[p] = Zx[p * ZPS + zi0];
#pragma unroll
    for (int p = 0; p < 8; ++p) zB[p] = Zx[p * ZPS + zi0 + 512];
    __syncthreads();                         // HtF zero-init visible (one-time drain ok)

#pragma unroll 1
    for (int t = 0; t < 128; t += 2) {
        LSTM_STEP(t,     zA, 0, 1);          // reads HtF[0], writes HtF[1]
        LSTM_STEP(t + 1, zB, 1, 0);          // reads HtF[1], writes HtF[0]
    }

    // ---- output projection: fp32 h -> bf16 staging tile -> MFMA ----
    for (int i = tid; i < 16 * LDH; i += 512) HtB[i] = (__bf16)0.f;
    __syncthreads();
#pragma unroll
    for (int hf = 0; hf < 2; ++hf)
        HtB[(4 * quad) * LDH + hf * 128 + col0] = (__bf16)hr[hf];
    __syncthreads();

    bf16x8 wo[8];
#pragma unroll
    for (int kt = 0; kt < 8; ++kt) {
        bf16x8 f;
#pragma unroll
        for (int j = 0; j < 8; ++j)
            f[j] = (__bf16)wout[(size_t)(kt * 32 + quad * 8 + j) * 128 + col0];
        wo[kt] = f;
    }
    f32x4 oa = {0.f, 0.f, 0.f, 0.f};
#pragma unroll
    for (int kt = 0; kt < 8; ++kt) {
        bf16x8 af = *(const bf16x8*)&HtB[l16 * LDH + kt * 32 + quad * 8];
        oa = mfma_bf16(af, wo[kt], oa);
    }
    if (quad == 0)                            // all quads hold identical oa[0]
        out[(size_t)R * 128 + col0] = oa[0] + bout[col0];
}

extern "C" void kernel_launch(void* const* d_in, const int* in_sizes, int n_in,
                              void* d_out, int out_size, void* d_ws, size_t ws_size,
                              hipStream_t stream) {
    const float* x    = (const float*)d_in[0];
    const float* Wk   = (const float*)d_in[1];
    const float* bias = (const float*)d_in[2];
    const float* wout = (const float*)d_in[3];
    const float* bout = (const float*)d_in[4];
    float* out = (float*)d_out;

    __bf16*        WxF = (__bf16*)d_ws;                      // 512 KB
    unsigned char* WhF = (unsigned char*)d_ws + 524288;      // 256 KB (fp8 MX frags)
    uint2*         Zx  = (uint2*)((char*)d_ws + 2097152);    // 128 MB, 8 planes

    shuffle_w<<<160, 256, 0, stream>>>(Wk, WxF, WhF);
    xproj<<<1024, 512, 0, stream>>>(x, WxF, bias, Zx);
    lstm_rec<<<512, 512, 0, stream>>>(WhF, Zx, wout, bout, out);
}

// Round 4
// 413.739 us; speedup vs baseline: 4.7070x; 4.7070x over previous
//
#include <hip/hip_runtime.h>
#include <hip/hip_fp16.h>
#include <stdint.h>
#include <stddef.h>

// LSTM B=512,T=128,D=256,H=256,C=128, gates (i,j,f,o), FORGET_BIAS=1.
// R13 = R9's PROVEN sync structure (__syncthreads everywhere; the inline-asm
// lgkm-only barrier of R10/R12 is rejected: R12 failed the post-timing
// determinism check -> latent inter-wave race around the hidden s_barrier)
// + only wave-private register-dataflow optimizations kept from R12:
//   a) z fp16->f32 extract hoisted one step early (uint2 ping-pong -> float
//      ping-pong, extracted in the post-MFMA shadow), folded into the MFMA
//      acc initializer {z,0,0,0} (fp32 C-accumulate, numerically identical).
//   b) z(t+2) reloads issued BEFORE the MFMA cluster so the __syncthreads
//      vmcnt(0) drain overlaps MFMA+epilogue (Zx is L3-resident).
//   c) s_setprio(1) around the MFMA cluster (correctness-neutral hint).

typedef __attribute__((ext_vector_type(8))) __bf16 bf16x8;
typedef __attribute__((ext_vector_type(4))) __bf16 bf16x4;
typedef __attribute__((ext_vector_type(4))) float  f32x4;
typedef __attribute__((ext_vector_type(8))) int    i32x8;

#define LDH   264          // bf16 row stride (xproj A-tile, out staging)
#define LDF   272          // fp8 Ht row stride in bytes (256 + 16)
#define ZPS   2097152ull   // Zx plane stride in uint2 (32*128*8*64)
#define SONE  0x7F7F7F7F   // E8M0 unit scales (all blocks = 2^0)

__device__ __forceinline__ f32x4 mfma_bf16(bf16x8 a, bf16x8 b, f32x4 c) {
    return __builtin_amdgcn_mfma_f32_16x16x32_bf16(a, b, c, 0, 0, 0);
}
#define EXP2(x) __builtin_amdgcn_exp2f(x)
#define RCP(x)  __builtin_amdgcn_rcpf(x)
#define L2E  1.442695040f
#define L2E2 2.885390082f

// ---------------- 1) weight shuffle ----------------
__global__ __launch_bounds__(256) void shuffle_w(const float* __restrict__ Wk,
                                                 __bf16* __restrict__ WxF,
                                                 unsigned char* __restrict__ WhF) {
    int id = blockIdx.x * 256 + threadIdx.x;
    if (id < 32768) {                                  // Wx part (rows 0..255)
        int lane = id & 63, kt = (id >> 6) & 7, nt = id >> 9;
        int quad = lane >> 4, l16 = lane & 15;
        const float* src = Wk + (size_t)(kt * 32 + quad * 8) * 1024 + nt * 16 + l16;
        __bf16* dst = WxF + ((size_t)(nt * 8 + kt) * 64 + lane) * 8;
#pragma unroll
        for (int j = 0; j < 8; ++j) dst[j] = (__bf16)src[(size_t)j * 1024];
    } else if (id < 40960) {                           // Wh part (rows 256..511)
        int i = id - 32768;
        int lane = i & 63, kt = (i >> 6) & 1, ng = i >> 7;
        int n = ng * 16 + (lane & 15);
        int kb = 256 + kt * 128 + (lane >> 4) * 32;
        int* dst = (int*)(WhF + (((size_t)ng * 2 + kt) * 64 + lane) * 32);
#pragma unroll
        for (int d = 0; d < 8; ++d) {
            float w0 = Wk[(size_t)(kb + 4 * d + 0) * 1024 + n];
            float w1 = Wk[(size_t)(kb + 4 * d + 1) * 1024 + n];
            float w2 = Wk[(size_t)(kb + 4 * d + 2) * 1024 + n];
            float w3 = Wk[(size_t)(kb + 4 * d + 3) * 1024 + n];
            int lo = __builtin_amdgcn_cvt_pk_fp8_f32(w0, w1, 0, false);
            dst[d]  = __builtin_amdgcn_cvt_pk_fp8_f32(w2, w3, lo, true);
        }
    }
}

// ---------------- 2) x-projection (plane-separated Zx) — as R5/R8 ----------------
__global__ __launch_bounds__(512, 2) void xproj(const float* __restrict__ x,
        const __bf16* __restrict__ WxF, const float* __restrict__ bias,
        uint2* __restrict__ Zx) {
    __shared__ __attribute__((aligned(16))) __bf16 At[64 * LDH];
    const int tid = threadIdx.x, wv = tid >> 6, lane = tid & 63;
    const int l16 = lane & 15, quad = lane >> 4;
    const int rb = blockIdx.x & 31, tg = blockIdx.x >> 5;

#pragma unroll
    for (int rr = 0; rr < 8; ++rr) {
        int Arow = wv * 8 + rr;
        int tt = Arow >> 4, r = Arow & 15;
        const float4 xv = *((const float4*)(x + ((size_t)(rb * 16 + r) * 128 + tg * 4 + tt) * 256) + lane);
        bf16x4 xb = { (__bf16)xv.x, (__bf16)xv.y, (__bf16)xv.z, (__bf16)xv.w };
        *(bf16x4*)&At[Arow * LDH + lane * 4] = xb;
    }
    __syncthreads();

    f32x4 acc[4][8];
#pragma unroll
    for (int tt = 0; tt < 4; ++tt)
#pragma unroll
        for (int nt = 0; nt < 8; ++nt) acc[tt][nt] = (f32x4){0.f, 0.f, 0.f, 0.f};

#pragma unroll
    for (int kt = 0; kt < 8; ++kt) {
        bf16x8 af[4];
#pragma unroll
        for (int tt = 0; tt < 4; ++tt)
            af[tt] = *(const bf16x8*)&At[(tt * 16 + l16) * LDH + kt * 32 + quad * 8];
#pragma unroll
        for (int nt = 0; nt < 8; ++nt) {
            bf16x8 wf = *(const bf16x8*)&WxF[(((size_t)(wv * 8 + nt) * 8 + kt) * 64 + lane) * 8];
#pragma unroll
            for (int tt = 0; tt < 4; ++tt) acc[tt][nt] = mfma_bf16(af[tt], wf, acc[tt][nt]);
        }
    }

#pragma unroll
    for (int nt = 0; nt < 8; ++nt) {
        int col = wv * 128 + nt * 16 + l16;
        float bb = bias[col] + ((col >= 512 && col < 768) ? 1.0f : 0.0f);
#pragma unroll
        for (int tt = 0; tt < 4; ++tt) {
            int t = tg * 4 + tt;
            union { __half h[4]; uint2 u; } pk;
#pragma unroll
            for (int r = 0; r < 4; ++r) pk.h[r] = __float2half(acc[tt][nt][r] + bb);
            Zx[(size_t)wv * ZPS + ((size_t)(rb * 128 + t) * 8 + nt) * 64 + lane] = pk.u;
        }
    }
}

// ---------------- 3) recurrent loop: 128 blocks x 4 batch rows ----------------
// Step body. ZZU holds pre-extracted z(t) floats; reload ZR <- z(t+2) is
// issued BEFORE the MFMA cluster (drain overlap); ZRE (loaded last step,
// z(t+1)) is extracted into ZZE in the post-MFMA shadow. Full __syncthreads
// publishes h(t+1) — architectural barrier, no hand-rolled asm.
#define LSTM_STEP(TT, ZR, ZZU, ZRE, ZZE, RBUF, WBUF)                           \
    {                                                                          \
        i32x8 afr[2];                                                          \
        _Pragma("unroll")                                                      \
        for (int kt = 0; kt < 2; ++kt) {                                       \
            const uint4* ap = (const uint4*)&HtF[RBUF][l16 * LDF + kt * 128 + quad * 32]; \
            uint4 lo = ap[0], hi = ap[1];                                      \
            afr[kt] = (i32x8){(int)lo.x, (int)lo.y, (int)lo.z, (int)lo.w,      \
                              (int)hi.x, (int)hi.y, (int)hi.z, (int)hi.w};     \
        }                                                                      \
        f32x4 acc[8];                                                          \
        _Pragma("unroll")                                                      \
        for (int p = 0; p < 8; ++p) acc[p] = (f32x4){ZZU[p], 0.f, 0.f, 0.f};   \
        {                                                                      \
            int tl = ((TT) + 2 > 127) ? 127 : ((TT) + 2);                      \
            size_t zi = zi0 + (size_t)tl * 512;                                \
            _Pragma("unroll")                                                  \
            for (int p = 0; p < 8; ++p) ZR[p] = Zx[p * ZPS + zi];              \
        }                                                                      \
        __builtin_amdgcn_s_setprio(1);                                         \
        _Pragma("unroll")                                                      \
        for (int kt = 0; kt < 2; ++kt)                                         \
            _Pragma("unroll")                                                  \
            for (int p = 0; p < 8; ++p)                                        \
                acc[p] = __builtin_amdgcn_mfma_scale_f32_16x16x128_f8f6f4(     \
                    afr[kt], wreg[p * 2 + kt], acc[p], 0, 0, 0, SONE, 0, SONE);\
        __builtin_amdgcn_s_setprio(0);                                         \
        _Pragma("unroll")                                                      \
        for (int p = 0; p < 8; ++p) {                                          \
            unsigned w = (quad & 2) ? ZRE[p].y : ZRE[p].x;                     \
            w = (quad & 1) ? (w >> 16) : (w & 0xffff);                         \
            union { unsigned short u; __half h; } cv; cv.u = (unsigned short)w;\
            ZZE[p] = __half2float(cv.h);                                       \
        }                                                                      \
        unsigned char* ldsw = &HtF[WBUF][0];                                   \
        _Pragma("unroll")                                                      \
        for (int hf = 0; hf < 2; ++hf) {                                       \
            float iv = acc[0 + hf][0];                                         \
            float jv = acc[2 + hf][0];                                         \
            float fv = acc[4 + hf][0];                                         \
            float ov = acc[6 + hf][0];                                         \
            float si = RCP(1.f + EXP2(-L2E * iv));                             \
            float sf = RCP(1.f + EXP2(-L2E * fv));                             \
            float so = RCP(1.f + EXP2(-L2E * ov));                             \
            float tj = 2.f * RCP(1.f + EXP2(-L2E2 * jv)) - 1.f;                \
            float c = c_[hf] * sf + si * tj;                                   \
            c_[hf] = c;                                                        \
            float tc = 2.f * RCP(1.f + EXP2(-L2E2 * c)) - 1.f;                 \
            float h = tc * so;                                                 \
            hr[hf] = h;                                                        \
            unsigned pb = (unsigned)__builtin_amdgcn_cvt_pk_fp8_f32(h, h, 0, false); \
            ldsw[(4 * quad) * LDF + hf * 128 + col0] = (unsigned char)pb;      \
        }                                                                      \
        __syncthreads();   /* publish h(t+1) — architectural barrier */        \
    }

__global__ __launch_bounds__(512, 2) void lstm_rec(const unsigned char* __restrict__ WhF,
        const uint2* __restrict__ Zx, const float* __restrict__ wout,
        const float* __restrict__ bout, float* __restrict__ out) {
    // Ht: plain fp8 matrix [16 rows][272 B], double-buffered. Rows m=4b hold
    // batch rows b=0..3; other rows stay zero (m-padding).
    __shared__ __attribute__((aligned(16))) unsigned char HtF[2][16 * LDF];
    __shared__ __attribute__((aligned(16))) __bf16 HtB[16 * LDH];   // out staging
    const int tid = threadIdx.x, wv = tid >> 6, lane = tid & 63;
    const int l16 = lane & 15, quad = lane >> 4;
    const int rbblk = blockIdx.x;            // batch rows 4*rbblk .. +3
    const int rb = rbblk >> 2, qb = rbblk & 3;

    // Wh MX B-frags: 16 x v8i32 = 128 regs (p = g*2+hf, kt128 = 0,1)
    i32x8 wreg[16];
#pragma unroll
    for (int p = 0; p < 8; ++p) {
        int ng = (p >> 1) * 16 + (p & 1) * 8 + wv;   // cols g*256+hf*128+wv*16+l16
#pragma unroll
        for (int kt = 0; kt < 2; ++kt) {
            const uint4* wp = (const uint4*)(WhF + (((size_t)ng * 2 + kt) * 64 + lane) * 32);
            uint4 lo = wp[0], hi = wp[1];
            wreg[p * 2 + kt] = (i32x8){(int)lo.x, (int)lo.y, (int)lo.z, (int)lo.w,
                                       (int)hi.x, (int)hi.y, (int)hi.z, (int)hi.w};
        }
    }
    for (int i = tid; i < (16 * LDF * 2) / 4; i += 512) ((uint*)HtF[0])[i] = 0u;

    const int col0 = wv * 16 + l16;
    float c_[2] = {0.f, 0.f};
    float hr[2] = {0.f, 0.f};
    const size_t zi0 = ((size_t)rb * 1024 + wv) * 64 + qb * 16 + l16;

    // raw ping-pong (uint2) + extracted-float ping-pong
    uint2 zrA[8], zrB[8];
    float zzA[8], zzB[8];
#pragma unroll
    for (int p = 0; p < 8; ++p) zrA[p] = Zx[p * ZPS + zi0];
#pragma unroll
    for (int p = 0; p < 8; ++p) zrB[p] = Zx[p * ZPS + zi0 + 512];
#pragma unroll
    for (int p = 0; p < 8; ++p) {            // pre-extract z(0) -> zzA
        unsigned w = (quad & 2) ? zrA[p].y : zrA[p].x;
        w = (quad & 1) ? (w >> 16) : (w & 0xffff);
        union { unsigned short u; __half h; } cv; cv.u = (unsigned short)w;
        zzA[p] = __half2float(cv.h);
    }
    __syncthreads();                         // HtF zero-init visible

#pragma unroll 1
    for (int t = 0; t < 128; t += 2) {
        // even: use zzA, reload zrA <- z(t+2), extract zrB(z(t+1)) -> zzB
        LSTM_STEP(t,     zrA, zzA, zrB, zzB, 0, 1);
        // odd:  use zzB, reload zrB <- z(t+3), extract zrA(z(t+2)) -> zzA
        LSTM_STEP(t + 1, zrB, zzB, zrA, zzA, 1, 0);
    }

    // ---- output projection: fp32 h -> bf16 staging tile -> MFMA ----
    for (int i = tid; i < 16 * LDH; i += 512) HtB[i] = (__bf16)0.f;
    __syncthreads();
#pragma unroll
    for (int hf = 0; hf < 2; ++hf)
        HtB[(4 * quad) * LDH + hf * 128 + col0] = (__bf16)hr[hf];
    __syncthreads();

    bf16x8 wo[8];
#pragma unroll
    for (int kt = 0; kt < 8; ++kt) {
        bf16x8 f;
#pragma unroll
        for (int j = 0; j < 8; ++j)
            f[j] = (__bf16)wout[(size_t)(kt * 32 + quad * 8 + j) * 128 + col0];
        wo[kt] = f;
    }
    f32x4 oa = {0.f, 0.f, 0.f, 0.f};
#pragma unroll
    for (int kt = 0; kt < 8; ++kt) {
        bf16x8 af = *(const bf16x8*)&HtB[l16 * LDH + kt * 32 + quad * 8];
        oa = mfma_bf16(af, wo[kt], oa);
    }
    out[(size_t)(rbblk * 4 + quad) * 128 + col0] = oa[0] + bout[col0];
}

extern "C" void kernel_launch(void* const* d_in, const int* in_sizes, int n_in,
                              void* d_out, int out_size, void* d_ws, size_t ws_size,
                              hipStream_t stream) {
    const float* x    = (const float*)d_in[0];
    const float* Wk   = (const float*)d_in[1];
    const float* bias = (const float*)d_in[2];
    const float* wout = (const float*)d_in[3];
    const float* bout = (const float*)d_in[4];
    float* out = (float*)d_out;

    __bf16*        WxF = (__bf16*)d_ws;                      // 512 KB
    unsigned char* WhF = (unsigned char*)d_ws + 524288;      // 256 KB (fp8 MX frags)
    uint2*         Zx  = (uint2*)((char*)d_ws + 2097152);    // 128 MB, 8 planes

    shuffle_w<<<160, 256, 0, stream>>>(Wk, WxF, WhF);
    xproj<<<1024, 512, 0, stream>>>(x, WxF, bias, Zx);
    lstm_rec<<<128, 512, 0, stream>>>(WhF, Zx, wout, bout, out);
}

// Round 6
// 410.822 us; speedup vs baseline: 4.7404x; 1.0071x over previous
//
#include <hip/hip_runtime.h>
#include <hip/hip_fp16.h>
#include <stdint.h>
#include <stddef.h>

// LSTM B=512,T=128,D=256,H=256,C=128, gates (i,j,f,o), FORGET_BIAS=1.
// R15 = R14 resubmitted verbatim (R5 bench was an infra failure: "MI355X
// container failed twice" — no kernel signal). Rationale unchanged:
//   xproj was ~160us at ~9% MFMA peak: acc[4][8]=128 regs forced 1 block/CU
//   (2 lockstep waves/SIMD), serializing stage->MFMA->epilogue phases.
//   New: M=32 rows/block (16 batch rows x 2 t-slices), grid 2048,
//   acc[2][8]=64 regs, launch_bounds(512,4) -> 2 blocks/CU, one block's
//   stage/epilogue overlaps the other's MFMA. Weight L2 traffic doubles to
//   1 GB but is XCD-L2-resident (512 KB working set).
//   lstm_rec is BIT-IDENTICAL to R13 (proven 241us, sound __syncthreads).

typedef __attribute__((ext_vector_type(8))) __bf16 bf16x8;
typedef __attribute__((ext_vector_type(4))) __bf16 bf16x4;
typedef __attribute__((ext_vector_type(4))) float  f32x4;
typedef __attribute__((ext_vector_type(8))) int    i32x8;

#define LDH   264          // bf16 row stride (xproj A-tile, out staging)
#define LDF   272          // fp8 Ht row stride in bytes (256 + 16)
#define ZPS   2097152ull   // Zx plane stride in uint2 (32*128*8*64)
#define SONE  0x7F7F7F7F   // E8M0 unit scales (all blocks = 2^0)

__device__ __forceinline__ f32x4 mfma_bf16(bf16x8 a, bf16x8 b, f32x4 c) {
    return __builtin_amdgcn_mfma_f32_16x16x32_bf16(a, b, c, 0, 0, 0);
}
#define EXP2(x) __builtin_amdgcn_exp2f(x)
#define RCP(x)  __builtin_amdgcn_rcpf(x)
#define L2E  1.442695040f
#define L2E2 2.885390082f

// ---------------- 1) weight shuffle ----------------
__global__ __launch_bounds__(256) void shuffle_w(const float* __restrict__ Wk,
                                                 __bf16* __restrict__ WxF,
                                                 unsigned char* __restrict__ WhF) {
    int id = blockIdx.x * 256 + threadIdx.x;
    if (id < 32768) {                                  // Wx part (rows 0..255)
        int lane = id & 63, kt = (id >> 6) & 7, nt = id >> 9;
        int quad = lane >> 4, l16 = lane & 15;
        const float* src = Wk + (size_t)(kt * 32 + quad * 8) * 1024 + nt * 16 + l16;
        __bf16* dst = WxF + ((size_t)(nt * 8 + kt) * 64 + lane) * 8;
#pragma unroll
        for (int j = 0; j < 8; ++j) dst[j] = (__bf16)src[(size_t)j * 1024];
    } else if (id < 40960) {                           // Wh part (rows 256..511)
        int i = id - 32768;
        int lane = i & 63, kt = (i >> 6) & 1, ng = i >> 7;
        int n = ng * 16 + (lane & 15);
        int kb = 256 + kt * 128 + (lane >> 4) * 32;
        int* dst = (int*)(WhF + (((size_t)ng * 2 + kt) * 64 + lane) * 32);
#pragma unroll
        for (int d = 0; d < 8; ++d) {
            float w0 = Wk[(size_t)(kb + 4 * d + 0) * 1024 + n];
            float w1 = Wk[(size_t)(kb + 4 * d + 1) * 1024 + n];
            float w2 = Wk[(size_t)(kb + 4 * d + 2) * 1024 + n];
            float w3 = Wk[(size_t)(kb + 4 * d + 3) * 1024 + n];
            int lo = __builtin_amdgcn_cvt_pk_fp8_f32(w0, w1, 0, false);
            dst[d]  = __builtin_amdgcn_cvt_pk_fp8_f32(w2, w3, lo, true);
        }
    }
}

// ---------------- 2) x-projection: M=32/block, 2 blocks/CU ----------------
// Block (rb, tg): batch rows rb*16..+15, t in {2*tg, 2*tg+1}. Per wave:
// acc[2][8] (=64 regs), 128 MFMA 16x16x32. Layouts in Zx unchanged vs R13.
__global__ __launch_bounds__(512, 4) void xproj(const float* __restrict__ x,
        const __bf16* __restrict__ WxF, const float* __restrict__ bias,
        uint2* __restrict__ Zx) {
    __shared__ __attribute__((aligned(16))) __bf16 At[32 * LDH];
    const int tid = threadIdx.x, wv = tid >> 6, lane = tid & 63;
    const int l16 = lane & 15, quad = lane >> 4;
    const int rb = blockIdx.x & 31, tg = blockIdx.x >> 5;   // tg 0..63

#pragma unroll
    for (int rr = 0; rr < 4; ++rr) {
        int Arow = wv * 4 + rr;                  // 32 A-rows: [tt=Arow>>4][r=Arow&15]
        int tt = Arow >> 4, r = Arow & 15;
        const float4 xv = *((const float4*)(x + ((size_t)(rb * 16 + r) * 128 + tg * 2 + tt) * 256) + lane);
        bf16x4 xb = { (__bf16)xv.x, (__bf16)xv.y, (__bf16)xv.z, (__bf16)xv.w };
        *(bf16x4*)&At[Arow * LDH + lane * 4] = xb;
    }
    __syncthreads();

    f32x4 acc[2][8];
#pragma unroll
    for (int tt = 0; tt < 2; ++tt)
#pragma unroll
        for (int nt = 0; nt < 8; ++nt) acc[tt][nt] = (f32x4){0.f, 0.f, 0.f, 0.f};

#pragma unroll
    for (int kt = 0; kt < 8; ++kt) {
        bf16x8 af[2];
#pragma unroll
        for (int tt = 0; tt < 2; ++tt)
            af[tt] = *(const bf16x8*)&At[(tt * 16 + l16) * LDH + kt * 32 + quad * 8];
#pragma unroll
        for (int nt = 0; nt < 8; ++nt) {
            bf16x8 wf = *(const bf16x8*)&WxF[(((size_t)(wv * 8 + nt) * 8 + kt) * 64 + lane) * 8];
#pragma unroll
            for (int tt = 0; tt < 2; ++tt) acc[tt][nt] = mfma_bf16(af[tt], wf, acc[tt][nt]);
        }
    }

#pragma unroll
    for (int nt = 0; nt < 8; ++nt) {
        int col = wv * 128 + nt * 16 + l16;
        float bb = bias[col] + ((col >= 512 && col < 768) ? 1.0f : 0.0f);
#pragma unroll
        for (int tt = 0; tt < 2; ++tt) {
            int t = tg * 2 + tt;
            union { __half h[4]; uint2 u; } pk;
#pragma unroll
            for (int r = 0; r < 4; ++r) pk.h[r] = __float2half(acc[tt][nt][r] + bb);
            Zx[(size_t)wv * ZPS + ((size_t)(rb * 128 + t) * 8 + nt) * 64 + lane] = pk.u;
        }
    }
}

// ---------------- 3) recurrent loop: 128 blocks x 4 batch rows ----------------
// BIT-IDENTICAL to R13 (proven sound + 241us).
#define LSTM_STEP(TT, ZR, ZZU, ZRE, ZZE, RBUF, WBUF)                           \
    {                                                                          \
        i32x8 afr[2];                                                          \
        _Pragma("unroll")                                                      \
        for (int kt = 0; kt < 2; ++kt) {                                       \
            const uint4* ap = (const uint4*)&HtF[RBUF][l16 * LDF + kt * 128 + quad * 32]; \
            uint4 lo = ap[0], hi = ap[1];                                      \
            afr[kt] = (i32x8){(int)lo.x, (int)lo.y, (int)lo.z, (int)lo.w,      \
                              (int)hi.x, (int)hi.y, (int)hi.z, (int)hi.w};     \
        }                                                                      \
        f32x4 acc[8];                                                          \
        _Pragma("unroll")                                                      \
        for (int p = 0; p < 8; ++p) acc[p] = (f32x4){ZZU[p], 0.f, 0.f, 0.f};   \
        {                                                                      \
            int tl = ((TT) + 2 > 127) ? 127 : ((TT) + 2);                      \
            size_t zi = zi0 + (size_t)tl * 512;                                \
            _Pragma("unroll")                                                  \
            for (int p = 0; p < 8; ++p) ZR[p] = Zx[p * ZPS + zi];              \
        }                                                                      \
        __builtin_amdgcn_s_setprio(1);                                         \
        _Pragma("unroll")                                                      \
        for (int kt = 0; kt < 2; ++kt)                                         \
            _Pragma("unroll")                                                  \
            for (int p = 0; p < 8; ++p)                                        \
                acc[p] = __builtin_amdgcn_mfma_scale_f32_16x16x128_f8f6f4(     \
                    afr[kt], wreg[p * 2 + kt], acc[p], 0, 0, 0, SONE, 0, SONE);\
        __builtin_amdgcn_s_setprio(0);                                         \
        _Pragma("unroll")                                                      \
        for (int p = 0; p < 8; ++p) {                                          \
            unsigned w = (quad & 2) ? ZRE[p].y : ZRE[p].x;                     \
            w = (quad & 1) ? (w >> 16) : (w & 0xffff);                         \
            union { unsigned short u; __half h; } cv; cv.u = (unsigned short)w;\
            ZZE[p] = __half2float(cv.h);                                       \
        }                                                                      \
        unsigned char* ldsw = &HtF[WBUF][0];                                   \
        _Pragma("unroll")                                                      \
        for (int hf = 0; hf < 2; ++hf) {                                       \
            float iv = acc[0 + hf][0];                                         \
            float jv = acc[2 + hf][0];                                         \
            float fv = acc[4 + hf][0];                                         \
            float ov = acc[6 + hf][0];                                         \
            float si = RCP(1.f + EXP2(-L2E * iv));                             \
            float sf = RCP(1.f + EXP2(-L2E * fv));                             \
            float so = RCP(1.f + EXP2(-L2E * ov));                             \
            float tj = 2.f * RCP(1.f + EXP2(-L2E2 * jv)) - 1.f;                \
            float c = c_[hf] * sf + si * tj;                                   \
            c_[hf] = c;                                                        \
            float tc = 2.f * RCP(1.f + EXP2(-L2E2 * c)) - 1.f;                 \
            float h = tc * so;                                                 \
            hr[hf] = h;                                                        \
            unsigned pb = (unsigned)__builtin_amdgcn_cvt_pk_fp8_f32(h, h, 0, false); \
            ldsw[(4 * quad) * LDF + hf * 128 + col0] = (unsigned char)pb;      \
        }                                                                      \
        __syncthreads();   /* publish h(t+1) — architectural barrier */        \
    }

__global__ __launch_bounds__(512, 2) void lstm_rec(const unsigned char* __restrict__ WhF,
        const uint2* __restrict__ Zx, const float* __restrict__ wout,
        const float* __restrict__ bout, float* __restrict__ out) {
    __shared__ __attribute__((aligned(16))) unsigned char HtF[2][16 * LDF];
    __shared__ __attribute__((aligned(16))) __bf16 HtB[16 * LDH];   // out staging
    const int tid = threadIdx.x, wv = tid >> 6, lane = tid & 63;
    const int l16 = lane & 15, quad = lane >> 4;
    const int rbblk = blockIdx.x;            // batch rows 4*rbblk .. +3
    const int rb = rbblk >> 2, qb = rbblk & 3;

    // Wh MX B-frags: 16 x v8i32 = 128 regs (p = g*2+hf, kt128 = 0,1)
    i32x8 wreg[16];
#pragma unroll
    for (int p = 0; p < 8; ++p) {
        int ng = (p >> 1) * 16 + (p & 1) * 8 + wv;   // cols g*256+hf*128+wv*16+l16
#pragma unroll
        for (int kt = 0; kt < 2; ++kt) {
            const uint4* wp = (const uint4*)(WhF + (((size_t)ng * 2 + kt) * 64 + lane) * 32);
            uint4 lo = wp[0], hi = wp[1];
            wreg[p * 2 + kt] = (i32x8){(int)lo.x, (int)lo.y, (int)lo.z, (int)lo.w,
                                       (int)hi.x, (int)hi.y, (int)hi.z, (int)hi.w};
        }
    }
    for (int i = tid; i < (16 * LDF * 2) / 4; i += 512) ((uint*)HtF[0])[i] = 0u;

    const int col0 = wv * 16 + l16;
    float c_[2] = {0.f, 0.f};
    float hr[2] = {0.f, 0.f};
    const size_t zi0 = ((size_t)rb * 1024 + wv) * 64 + qb * 16 + l16;

    // raw ping-pong (uint2) + extracted-float ping-pong
    uint2 zrA[8], zrB[8];
    float zzA[8], zzB[8];
#pragma unroll
    for (int p = 0; p < 8; ++p) zrA[p] = Zx[p * ZPS + zi0];
#pragma unroll
    for (int p = 0; p < 8; ++p) zrB[p] = Zx[p * ZPS + zi0 + 512];
#pragma unroll
    for (int p = 0; p < 8; ++p) {            // pre-extract z(0) -> zzA
        unsigned w = (quad & 2) ? zrA[p].y : zrA[p].x;
        w = (quad & 1) ? (w >> 16) : (w & 0xffff);
        union { unsigned short u; __half h; } cv; cv.u = (unsigned short)w;
        zzA[p] = __half2float(cv.h);
    }
    __syncthreads();                         // HtF zero-init visible

#pragma unroll 1
    for (int t = 0; t < 128; t += 2) {
        // even: use zzA, reload zrA <- z(t+2), extract zrB(z(t+1)) -> zzB
        LSTM_STEP(t,     zrA, zzA, zrB, zzB, 0, 1);
        // odd:  use zzB, reload zrB <- z(t+3), extract zrA(z(t+2)) -> zzA
        LSTM_STEP(t + 1, zrB, zzB, zrA, zzA, 1, 0);
    }

    // ---- output projection: fp32 h -> bf16 staging tile -> MFMA ----
    for (int i = tid; i < 16 * LDH; i += 512) HtB[i] = (__bf16)0.f;
    __syncthreads();
#pragma unroll
    for (int hf = 0; hf < 2; ++hf)
        HtB[(4 * quad) * LDH + hf * 128 + col0] = (__bf16)hr[hf];
    __syncthreads();

    bf16x8 wo[8];
#pragma unroll
    for (int kt = 0; kt < 8; ++kt) {
        bf16x8 f;
#pragma unroll
        for (int j = 0; j < 8; ++j)
            f[j] = (__bf16)wout[(size_t)(kt * 32 + quad * 8 + j) * 128 + col0];
        wo[kt] = f;
    }
    f32x4 oa = {0.f, 0.f, 0.f, 0.f};
#pragma unroll
    for (int kt = 0; kt < 8; ++kt) {
        bf16x8 af = *(const bf16x8*)&HtB[l16 * LDH + kt * 32 + quad * 8];
        oa = mfma_bf16(af, wo[kt], oa);
    }
    out[(size_t)(rbblk * 4 + quad) * 128 + col0] = oa[0] + bout[col0];
}

extern "C" void kernel_launch(void* const* d_in, const int* in_sizes, int n_in,
                              void* d_out, int out_size, void* d_ws, size_t ws_size,
                              hipStream_t stream) {
    const float* x    = (const float*)d_in[0];
    const float* Wk   = (const float*)d_in[1];
    const float* bias = (const float*)d_in[2];
    const float* wout = (const float*)d_in[3];
    const float* bout = (const float*)d_in[4];
    float* out = (float*)d_out;

    __bf16*        WxF = (__bf16*)d_ws;                      // 512 KB
    unsigned char* WhF = (unsigned char*)d_ws + 524288;      // 256 KB (fp8 MX frags)
    uint2*         Zx  = (uint2*)((char*)d_ws + 2097152);    // 128 MB, 8 planes

    shuffle_w<<<160, 256, 0, stream>>>(Wk, WxF, WhF);
    xproj<<<2048, 512, 0, stream>>>(x, WxF, bias, Zx);
    lstm_rec<<<128, 512, 0, stream>>>(WhF, Zx, wout, bout, out);
}